// Round 18
// baseline (251.500 us; speedup 1.0000x reference)
//
#include <hip/hip_runtime.h>
#include <hip/hip_bf16.h>

// ---------------------------------------------------------------------------
// 2-layer GCN, N=100000 nodes, E=3200000 edges, 128 -> 64 -> 64.
// out[i] = dinv[i] * ( sum_{e: dst=i} g[src_e] + g[i] ) + b,  g = (x@W)*dinv,
// dinv = rsqrt(indeg+1).
//
// Structure: CSR build with zero global atomics / ~1x write amplification
//   (localsort -> colscan -> fhist/frowp/fscat), then
//   gemm128 -> agg1(relu, bf16 h) -> gemm64(bf16 in) -> agg2, G in bf16.
//
// Locked-in lessons:
//  - agg: wave = 2 packed edge-streams (uint = 2 bf16), unroll 16 -> 32 lines
//    in flight/wave. MLP curve 8/16/32-lines: 91/75/71.5us — near the
//    L2<->L3 fill service wall (FETCH 160MB @ 2.24TB/s, ~1 line/cy/XCD).
//  - CHUNK=8192 / CB=1024: full-wave segment loads in fhist/fscat (r16 win).
//  - monolithic fine pass was latency-bound (r13) -> 8 XCD-pinned sub-blocks.
//  - Do NOT feature-slice (r8); do NOT fuse matvec into gather wave (r9);
//    no LDS-tile accumulate (r3); no single-cursor scatter (r4/r5);
//    no nontemporal on multi-use streams (r11).
// ---------------------------------------------------------------------------

#define CHUNK 8192      // edges per localsort block
#define CB    1024      // nodes per coarse bucket (<=128 buckets, u8 keys)

typedef int i32x2 __attribute__((ext_vector_type(2)));
typedef int i32x4 __attribute__((ext_vector_type(4)));
typedef unsigned short u16x4 __attribute__((ext_vector_type(4)));

__device__ __forceinline__ unsigned short f2bf(float f) {
    union { float f; unsigned int u; } x; x.f = f;
    unsigned int r = (x.u + 0x7FFF + ((x.u >> 16) & 1)) >> 16;  // RNE
    return (unsigned short)r;
}
__device__ __forceinline__ float bf2f(unsigned short u) {
    union { unsigned int u; float f; } x; x.u = ((unsigned int)u) << 16;
    return x.f;
}
__device__ __forceinline__ float bflo(unsigned v) {
    union { unsigned int u; float f; } x; x.u = v << 16;
    return x.f;
}
__device__ __forceinline__ float bfhi(unsigned v) {
    union { unsigned int u; float f; } x; x.u = v & 0xFFFF0000u;
    return x.f;
}

// ---------------------------------------------------------------------------
// Pass 1: per-chunk LDS counting sort by coarse bucket (d >> 10).
// Self-detects int32 vs int64 edge layout; paired 16B/8B loads when aligned.
// ---------------------------------------------------------------------------
__global__ __launch_bounds__(512) void k_localsort(const int* __restrict__ ei,
                                                   int* __restrict__ sorted_all,
                                                   int* __restrict__ off_local,
                                                   long long E, int NC) {
    __shared__ unsigned int  val[CHUNK];
    __shared__ unsigned char key[CHUNK];
    __shared__ unsigned int  srt[CHUNK];
    __shared__ int cnt[256], pos[256], cur[256];
    __shared__ int det;
    const int b = blockIdx.x;
    const int t = threadIdx.x;
    const long long base = (long long)b * CHUNK;
    const int nE = (int)((E - base < CHUNK) ? (E - base) : CHUNK);

    if (t == 0) det = 0;
    __syncthreads();
    {
        int step = nE > 512 ? nE / 512 : 1;
        long long i = (long long)t * step;
        if (i < nE && ei[2 * (base + i) + 1] != 0) atomicOr(&det, 1);
    }
    if (t < 256) cnt[t] = 0;
    __syncthreads();
    const int is32 = det;
    const bool evenE = ((E & 1LL) == 0);

    if (is32) {
        if (evenE) {
            for (int i = 2 * t; i + 1 < nE; i += 1024) {
                i32x2 sv = *(const i32x2*)&ei[base + i];
                i32x2 dv = *(const i32x2*)&ei[E + base + i];
#pragma unroll
                for (int k = 0; k < 2; ++k) {
                    int s = sv[k], d = dv[k];
                    val[i + k] = (unsigned)s | ((unsigned)(d & (CB - 1)) << 17);
                    key[i + k] = (unsigned char)(d >> 10);
                }
            }
            if ((nE & 1) && t == 0) {
                int i = nE - 1;
                int s = ei[base + i], d = ei[E + base + i];
                val[i] = (unsigned)s | ((unsigned)(d & (CB - 1)) << 17);
                key[i] = (unsigned char)(d >> 10);
            }
        } else {
            for (int i = t; i < nE; i += 512) {
                int s = ei[base + i];
                int d = ei[E + base + i];
                val[i] = (unsigned)s | ((unsigned)(d & (CB - 1)) << 17);
                key[i] = (unsigned char)(d >> 10);
            }
        }
    } else {
        if (evenE) {
            for (int i = 2 * t; i + 1 < nE; i += 1024) {
                i32x4 sv = *(const i32x4*)&ei[2 * (base + i)];
                i32x4 dv = *(const i32x4*)&ei[2 * (E + base + i)];
                int s0 = sv[0], s1 = sv[2];
                int d0 = dv[0], d1 = dv[2];
                val[i] = (unsigned)s0 | ((unsigned)(d0 & (CB - 1)) << 17);
                key[i] = (unsigned char)(d0 >> 10);
                val[i + 1] = (unsigned)s1 | ((unsigned)(d1 & (CB - 1)) << 17);
                key[i + 1] = (unsigned char)(d1 >> 10);
            }
            if ((nE & 1) && t == 0) {
                int i = nE - 1;
                const i32x2* ei2 = (const i32x2*)ei;
                int s = ei2[base + i][0];
                int d = ei2[E + base + i][0];
                val[i] = (unsigned)s | ((unsigned)(d & (CB - 1)) << 17);
                key[i] = (unsigned char)(d >> 10);
            }
        } else {
            const i32x2* ei2 = (const i32x2*)ei;
            for (int i = t; i < nE; i += 512) {
                int s = ei2[base + i][0];
                int d = ei2[E + base + i][0];
                val[i] = (unsigned)s | ((unsigned)(d & (CB - 1)) << 17);
                key[i] = (unsigned char)(d >> 10);
            }
        }
    }
    __syncthreads();
    for (int i = t; i < nE; i += 512) atomicAdd(&cnt[key[i]], 1);
    __syncthreads();
    if (t < 256) pos[t] = cnt[t];
    __syncthreads();
    for (int d = 1; d < 256; d <<= 1) {
        int x = (t >= d && t < 256) ? pos[t - d] : 0;
        __syncthreads();
        if (t < 256) pos[t] += x;
        __syncthreads();
    }
    if (t < 256) cur[t] = pos[t] - cnt[t];          // exclusive offset
    if (t < NC) off_local[b * (NC + 1) + t] = pos[t] - cnt[t];
    if (t == 0) off_local[b * (NC + 1) + NC] = nE;
    __syncthreads();
    for (int i = t; i < nE; i += 512) {
        int k = key[i];
        int p = atomicAdd(&cur[k], 1);
        srt[p] = val[i];
    }
    __syncthreads();
    for (int i = t; i < nE; i += 512) sorted_all[base + i] = (int)srt[i];
}

// ---------------------------------------------------------------------------
// Fused column-sum + exclusive scan (NC <= 128): per-bucket totals -> cbase,
// rowp[n] = E. One block, 1024 threads (8 partial sums per column).
// ---------------------------------------------------------------------------
__global__ __launch_bounds__(1024) void k_colscan(const int* __restrict__ off_local,
                                                  int* __restrict__ cbase,
                                                  int* __restrict__ rowp,
                                                  int nchunk, int NC, int n) {
    __shared__ int part[1024];
    __shared__ int tot[128];
    const int t = threadIdx.x;
    const int c = t & 127;
    const int g = t >> 7;                      // 0..7
    int sum = 0;
    if (c < NC) {
        for (int b = g; b < nchunk; b += 8) {
            int rb = b * (NC + 1);
            sum += off_local[rb + c + 1] - off_local[rb + c];
        }
    }
    part[t] = sum;
    __syncthreads();
    if (g == 0) {
        int s = 0;
#pragma unroll
        for (int k = 0; k < 8; ++k) s += part[k * 128 + c];
        tot[c] = s;
    }
    __syncthreads();
    if (t < 128) part[t] = (t < NC) ? tot[t] : 0;
    __syncthreads();
    for (int d = 1; d < 128; d <<= 1) {
        int x = (t >= d && t < 128) ? part[t - d] : 0;
        __syncthreads();
        if (t < 128) part[t] += x;
        __syncthreads();
    }
    if (t < NC) cbase[t] = part[t] - tot[t];
    if (t == NC - 1) { cbase[NC] = part[t]; rowp[n] = part[t]; }
}

// ---------------------------------------------------------------------------
// Fine pass, 8 XCD-pinned sub-blocks per bucket.
// ---------------------------------------------------------------------------
__global__ __launch_bounds__(512) void k_fhist(const int* __restrict__ sorted_all,
                                               const int* __restrict__ off_local,
                                               int* __restrict__ gsub,
                                               int nchunk, int NC) {
    __shared__ int hist[CB];
    const int x = blockIdx.x & 7;
    const int s = (blockIdx.x >> 3) & 7;
    const int c = (blockIdx.x >> 6) * 8 + x;
    if (c >= NC) return;
    const int t = threadIdx.x;
    const int w = t >> 6, lane = t & 63;
    hist[t] = 0;
    hist[t + 512] = 0;
    __syncthreads();
    const int span = (nchunk + 7) / 8;
    const int b0 = s * span;
    const int b1 = min(nchunk, b0 + span);
    for (int b = b0 + w; b < b1; b += 8) {
        int rb = b * (NC + 1);
        int s0 = b * CHUNK + off_local[rb + c];
        int s1 = b * CHUNK + off_local[rb + c + 1];
        for (int i = s0 + lane; i < s1; i += 64)
            atomicAdd(&hist[((unsigned)sorted_all[i] >> 17) & (CB - 1)], 1);
    }
    __syncthreads();
    gsub[((size_t)c * 8 + s) * CB + t] = hist[t];
    gsub[((size_t)c * 8 + s) * CB + t + 512] = hist[t + 512];
}

// Per-bucket: total hist -> rowp/dinv; per-sub cursors scur (exact ranges).
__global__ __launch_bounds__(1024) void k_frowp(const int* __restrict__ gsub,
                                                const int* __restrict__ cbase,
                                                int* __restrict__ scur,
                                                int* __restrict__ rowp,
                                                float* __restrict__ dinv,
                                                int NC, int n) {
    __shared__ int ssum[CB];
    const int c = blockIdx.x;
    const int t = threadIdx.x;                 // = dloc
    int h[8];
    int tot = 0;
#pragma unroll
    for (int s = 0; s < 8; ++s) {
        h[s] = gsub[((size_t)c * 8 + s) * CB + t];
        tot += h[s];
    }
    ssum[t] = tot;
    __syncthreads();
    for (int d = 1; d < 1024; d <<= 1) {
        int x = (t >= d) ? ssum[t - d] : 0;
        __syncthreads();
        ssum[t] += x;
        __syncthreads();
    }
    int base = cbase[c] + ssum[t] - tot;       // exclusive within bucket
    const int node = c * CB + t;
    if (node < n) {
        rowp[node] = base;
        dinv[node] = rsqrtf((float)(tot + 1));  // +1 self loop
    }
    int run = base;
#pragma unroll
    for (int s = 0; s < 8; ++s) {
        scur[((size_t)c * 8 + s) * CB + t] = run;
        run += h[s];
    }
}

// Scatter: each sub-block writes its private, disjoint per-dloc ranges.
__global__ __launch_bounds__(512) void k_fscat(const int* __restrict__ sorted_all,
                                               const int* __restrict__ off_local,
                                               const int* __restrict__ scur,
                                               int* __restrict__ esrc,
                                               int nchunk, int NC) {
    __shared__ int cur[CB];
    const int x = blockIdx.x & 7;
    const int s = (blockIdx.x >> 3) & 7;
    const int c = (blockIdx.x >> 6) * 8 + x;
    if (c >= NC) return;
    const int t = threadIdx.x;
    const int w = t >> 6, lane = t & 63;
    cur[t] = scur[((size_t)c * 8 + s) * CB + t];
    cur[t + 512] = scur[((size_t)c * 8 + s) * CB + t + 512];
    __syncthreads();
    const int span = (nchunk + 7) / 8;
    const int b0 = s * span;
    const int b1 = min(nchunk, b0 + span);
    for (int b = b0 + w; b < b1; b += 8) {
        int rb = b * (NC + 1);
        int s0 = b * CHUNK + off_local[rb + c];
        int s1 = b * CHUNK + off_local[rb + c + 1];
        for (int i = s0 + lane; i < s1; i += 64) {
            unsigned v = (unsigned)sorted_all[i];
            int dl = (v >> 17) & (CB - 1);
            int p = atomicAdd(&cur[dl], 1);
            esrc[p] = (int)(v & 0x1FFFF);
        }
    }
}

// ---------------------------------------------------------------------------
// Register-tiled GEMM: G[n x 64](bf16) = (X[n x K_IN] * W) * dinv.
// ---------------------------------------------------------------------------
template <int K_IN, bool BF16IN>
__global__ __launch_bounds__(256) void k_gemm2(const void* __restrict__ Xv,
                                               const float* __restrict__ W,
                                               const float* __restrict__ dinv,
                                               unsigned short* __restrict__ G,
                                               int n) {
    __shared__ float Xs[64][33];
    __shared__ float Ws[32][64];
    const int t = threadIdx.x;
    const int tx = t & 15;
    const int ty = t >> 4;
    const int r0 = blockIdx.x * 64;

    float acc[4][4] = {};

    for (int kb = 0; kb < K_IN; kb += 32) {
        {
            const int kq = t & 7;
            const int rr = t >> 3;
#pragma unroll
            for (int it = 0; it < 2; ++it) {
                int r = r0 + rr + it * 32;
                int rc = r < n ? r : n - 1;
                float* xd = &Xs[rr + it * 32][kq * 4];
                if (BF16IN) {
                    const unsigned short* X = (const unsigned short*)Xv;
                    u16x4 xv = *(const u16x4*)(X + (size_t)rc * K_IN + kb + kq * 4);
                    xd[0] = bf2f(xv[0]); xd[1] = bf2f(xv[1]);
                    xd[2] = bf2f(xv[2]); xd[3] = bf2f(xv[3]);
                } else {
                    const float* X = (const float*)Xv;
                    float4 xv = *(const float4*)(X + (size_t)rc * K_IN + kb + kq * 4);
                    xd[0] = xv.x; xd[1] = xv.y; xd[2] = xv.z; xd[3] = xv.w;
                }
            }
        }
        {
            const int cq = t & 15;
            const int kr = t >> 4;
#pragma unroll
            for (int it = 0; it < 2; ++it) {
                float4 wv = *(const float4*)(W + (size_t)(kb + kr + it * 16) * 64 + cq * 4);
                *(float4*)&Ws[kr + it * 16][cq * 4] = wv;
            }
        }
        __syncthreads();
#pragma unroll 8
        for (int k = 0; k < 32; ++k) {
            float4 wv = *(const float4*)&Ws[k][tx * 4];
            float x0 = Xs[ty * 4 + 0][k];
            float x1 = Xs[ty * 4 + 1][k];
            float x2 = Xs[ty * 4 + 2][k];
            float x3 = Xs[ty * 4 + 3][k];
            acc[0][0] = fmaf(x0, wv.x, acc[0][0]);
            acc[0][1] = fmaf(x0, wv.y, acc[0][1]);
            acc[0][2] = fmaf(x0, wv.z, acc[0][2]);
            acc[0][3] = fmaf(x0, wv.w, acc[0][3]);
            acc[1][0] = fmaf(x1, wv.x, acc[1][0]);
            acc[1][1] = fmaf(x1, wv.y, acc[1][1]);
            acc[1][2] = fmaf(x1, wv.z, acc[1][2]);
            acc[1][3] = fmaf(x1, wv.w, acc[1][3]);
            acc[2][0] = fmaf(x2, wv.x, acc[2][0]);
            acc[2][1] = fmaf(x2, wv.y, acc[2][1]);
            acc[2][2] = fmaf(x2, wv.z, acc[2][2]);
            acc[2][3] = fmaf(x2, wv.w, acc[2][3]);
            acc[3][0] = fmaf(x3, wv.x, acc[3][0]);
            acc[3][1] = fmaf(x3, wv.y, acc[3][1]);
            acc[3][2] = fmaf(x3, wv.z, acc[3][2]);
            acc[3][3] = fmaf(x3, wv.w, acc[3][3]);
        }
        __syncthreads();
    }
#pragma unroll
    for (int j = 0; j < 4; ++j) {
        int r = r0 + ty * 4 + j;
        if (r < n) {
            float dv = dinv[r];
            union { unsigned short u[4]; uint2 v; } o;
            o.u[0] = f2bf(acc[j][0] * dv);
            o.u[1] = f2bf(acc[j][1] * dv);
            o.u[2] = f2bf(acc[j][2] * dv);
            o.u[3] = f2bf(acc[j][3] * dv);
            *(uint2*)(G + (size_t)r * 64 + tx * 4) = o.v;
        }
    }
}

// ---------------------------------------------------------------------------
// Aggregation (dual-row packed, r17): wave = 2 edge streams x 32 feature-pair
// lanes; one instruction fetches 2 rows (2 x 128B lines). f32 accumulate,
// halves combined by shfl_xor(32). Self-loop on half 0 only.
// ---------------------------------------------------------------------------
template <bool RELU>
__global__ __launch_bounds__(256) void k_agg(const unsigned short* __restrict__ G,
                                             const int* __restrict__ rowp,
                                             const int* __restrict__ esrc,
                                             const float* __restrict__ dinv,
                                             const float* __restrict__ bias,
                                             void* __restrict__ OUTv, int n) {
    const int lane = threadIdx.x & 63;
    const int h = lane >> 5;                   // edge-stream half
    const int o = lane & 31;                   // feature pair index
    const int i = blockIdx.x * (blockDim.x >> 6) + (threadIdx.x >> 6);
    if (i >= n) return;
    const unsigned* __restrict__ Gu = (const unsigned*)G;   // row = 32 uints
    float a0 = 0.f, a1 = 0.f;
    if (h == 0) {
        unsigned sv = Gu[(size_t)i * 32 + o];              // self loop (once)
        a0 += bflo(sv); a1 += bfhi(sv);
    }
    int e = rowp[i] + h;
    const int e1 = rowp[i + 1];
    for (; e + 30 < e1; e += 32) {             // 16 rows per half per iter
        int s[16];
#pragma unroll
        for (int k = 0; k < 16; ++k) s[k] = esrc[e + 2 * k];
        unsigned v[16];
#pragma unroll
        for (int k = 0; k < 16; ++k) v[k] = Gu[(size_t)s[k] * 32 + o];
        float f0[8], f1[8];
#pragma unroll
        for (int k = 0; k < 8; ++k) {
            f0[k] = bflo(v[k]) + bflo(v[k + 8]);
            f1[k] = bfhi(v[k]) + bfhi(v[k + 8]);
        }
#pragma unroll
        for (int st = 4; st > 0; st >>= 1)
#pragma unroll
            for (int k = 0; k < st; ++k) { f0[k] += f0[k + st]; f1[k] += f1[k + st]; }
        a0 += f0[0]; a1 += f1[0];
    }
    for (; e + 6 < e1; e += 8) {               // 4 rows per half per iter
        int s[4];
#pragma unroll
        for (int k = 0; k < 4; ++k) s[k] = esrc[e + 2 * k];
#pragma unroll
        for (int k = 0; k < 4; ++k) {
            unsigned v = Gu[(size_t)s[k] * 32 + o];
            a0 += bflo(v); a1 += bfhi(v);
        }
    }
    for (; e < e1; e += 2) {
        unsigned v = Gu[(size_t)esrc[e] * 32 + o];
        a0 += bflo(v); a1 += bfhi(v);
    }
    a0 += __shfl_xor(a0, 32, 64);
    a1 += __shfl_xor(a1, 32, 64);
    if (h == 0) {
        float dv = dinv[i];
        float r0 = dv * a0 + bias[2 * o];
        float r1 = dv * a1 + bias[2 * o + 1];
        if (RELU) {
            r0 = fmaxf(r0, 0.f);
            r1 = fmaxf(r1, 0.f);
            unsigned pk = (unsigned)f2bf(r0) | ((unsigned)f2bf(r1) << 16);
            ((unsigned*)OUTv)[(size_t)i * 32 + o] = pk;
        } else {
            float2 r;
            r.x = r0; r.y = r1;
            *(float2*)((float*)OUTv + (size_t)i * 64 + 2 * o) = r;
        }
    }
}

extern "C" void kernel_launch(void* const* d_in, const int* in_sizes, int n_in,
                              void* d_out, int out_size, void* d_ws, size_t ws_size,
                              hipStream_t stream) {
    const float* x = (const float*)d_in[0];
    const int* ei = (const int*)d_in[1];
    const float* W1 = (const float*)d_in[2];
    const float* b1 = (const float*)d_in[3];
    const float* W2 = (const float*)d_in[4];
    const float* b2 = (const float*)d_in[5];
    float* out = (float*)d_out;

    const int N = in_sizes[0] / 128;          // requires N <= 131072 (17-bit src)
    const long long E = in_sizes[1] / 2;
    const int NCHUNK = (int)((E + CHUNK - 1) / CHUNK);
    const int NC = (N + CB - 1) / CB;                    // coarse buckets <= 128
    const int NBF = ((NC + 7) / 8) * 64;                 // fine-pass grid

    char* p = (char*)d_ws;
    size_t off = 0;
    auto take = [&](size_t bytes) -> void* {
        void* r = p + off;
        off += (bytes + 255) & ~(size_t)255;
        return r;
    };
    int* off_local = (int*)take((size_t)NCHUNK * (NC + 1) * 4);
    int* cbase = (int*)take((size_t)(NC + 1) * 4);
    int* rowp = (int*)take((size_t)(N + 1) * 4);
    float* dinv = (float*)take((size_t)N * 4);
    int* sorted_all = (int*)take((size_t)NCHUNK * CHUNK * 4);
    int* esrc = (int*)take((size_t)E * 4);
    int* gsub = (int*)take((size_t)NC * 8 * CB * 4);
    int* scur = (int*)take((size_t)NC * 8 * CB * 4);
    unsigned short* gbuf1 = (unsigned short*)take((size_t)N * 64 * 2);
    unsigned short* gbuf2 = (unsigned short*)take((size_t)N * 64 * 2);
    unsigned short* hbuf = (unsigned short*)take((size_t)N * 64 * 2);
    (void)ws_size; (void)n_in; (void)out_size;

    k_localsort<<<NCHUNK, 512, 0, stream>>>(ei, sorted_all, off_local, E, NC);
    k_colscan<<<1, 1024, 0, stream>>>(off_local, cbase, rowp, NCHUNK, NC, N);
    k_fhist<<<NBF, 512, 0, stream>>>(sorted_all, off_local, gsub, NCHUNK, NC);
    k_frowp<<<NC, 1024, 0, stream>>>(gsub, cbase, scur, rowp, dinv, NC, N);
    k_fscat<<<NBF, 512, 0, stream>>>(sorted_all, off_local, scur, esrc, NCHUNK, NC);

    k_gemm2<128, false><<<(N + 63) / 64, 256, 0, stream>>>(x, W1, dinv, gbuf1, N);
    k_agg<true><<<(N + 3) / 4, 256, 0, stream>>>(gbuf1, rowp, esrc, dinv, b1, hbuf, N);
    k_gemm2<64, true><<<(N + 63) / 64, 256, 0, stream>>>(hbuf, W2, dinv, gbuf2, N);
    k_agg<false><<<(N + 3) / 4, 256, 0, stream>>>(gbuf2, rowp, esrc, dinv, b2, out, N);
}

// Round 19
// 245.397 us; speedup vs baseline: 1.0249x; 1.0249x over previous
//
#include <hip/hip_runtime.h>
#include <hip/hip_bf16.h>

// ---------------------------------------------------------------------------
// 2-layer GCN, N=100000 nodes, E=3200000 edges, 128 -> 64 -> 64.
// out[i] = dinv[i] * ( sum_{e: dst=i} g[src_e] + g[i] ) + b,  g = (x@W)*dinv,
// dinv = rsqrt(indeg+1).
//
// Structure: CSR build with zero global atomics / ~1x write amplification
//   (localsort -> colsum -> cscan -> fhist/frowp/fscat), then
//   gemm128 -> agg1(relu, bf16 h) -> gemm64(bf16 in) -> agg2, G in bf16.
//
// FINAL configuration (= round-17, the measured best: 245.5us).
// Locked-in lessons:
//  - agg: wave = 2 packed edge-streams (uint = 2 bf16), unroll 16 -> 32 lines
//    in flight/wave. MLP curve 8/16/32-lines: 91/75/71.5us — at the L2<->L3
//    fill service wall (FETCH 160MB @ ~2.4TB/s, ~1 line/cy/XCD, 91% model).
//  - CHUNK=8192 / CB=1024: full-wave segment loads in fhist/fscat.
//  - monolithic fine pass was latency-bound (r13) -> 8 XCD-pinned sub-blocks.
//  - Do NOT feature-slice (r8: transaction-bound, 4x worse); do NOT fuse
//    matvec into gather wave (r9); no LDS-tile accumulate (r3); no
//    single-cursor scatter (r4/r5: 9-13x write amp); no nontemporal on
//    multi-use streams (r11); no paired-load localsort / colscan fusion
//    (r18: neutral-to-negative).
// ---------------------------------------------------------------------------

#define CHUNK 8192      // edges per localsort block
#define CB    1024      // nodes per coarse bucket (<=128 buckets, u8 keys)

typedef int i32x2 __attribute__((ext_vector_type(2)));
typedef unsigned short u16x4 __attribute__((ext_vector_type(4)));

__device__ __forceinline__ unsigned short f2bf(float f) {
    union { float f; unsigned int u; } x; x.f = f;
    unsigned int r = (x.u + 0x7FFF + ((x.u >> 16) & 1)) >> 16;  // RNE
    return (unsigned short)r;
}
__device__ __forceinline__ float bf2f(unsigned short u) {
    union { unsigned int u; float f; } x; x.u = ((unsigned int)u) << 16;
    return x.f;
}
__device__ __forceinline__ float bflo(unsigned v) {
    union { unsigned int u; float f; } x; x.u = v << 16;
    return x.f;
}
__device__ __forceinline__ float bfhi(unsigned v) {
    union { unsigned int u; float f; } x; x.u = v & 0xFFFF0000u;
    return x.f;
}

// ---------------------------------------------------------------------------
// Pass 1: per-chunk LDS counting sort by coarse bucket (d >> 10).
// Self-detects int32 vs int64 edge layout from its own chunk.
// ---------------------------------------------------------------------------
__global__ __launch_bounds__(512) void k_localsort(const int* __restrict__ ei,
                                                   int* __restrict__ sorted_all,
                                                   int* __restrict__ off_local,
                                                   long long E, int NC) {
    __shared__ unsigned int  val[CHUNK];
    __shared__ unsigned char key[CHUNK];
    __shared__ unsigned int  srt[CHUNK];
    __shared__ int cnt[256], pos[256], cur[256];
    __shared__ int det;
    const int b = blockIdx.x;
    const int t = threadIdx.x;
    const long long base = (long long)b * CHUNK;
    const int nE = (int)((E - base < CHUNK) ? (E - base) : CHUNK);

    if (t == 0) det = 0;
    __syncthreads();
    {
        int step = nE > 512 ? nE / 512 : 1;
        long long i = (long long)t * step;
        if (i < nE && ei[2 * (base + i) + 1] != 0) atomicOr(&det, 1);
    }
    if (t < 256) cnt[t] = 0;
    __syncthreads();
    const int is32 = det;

    if (is32) {
        for (int i = t; i < nE; i += 512) {
            int s = ei[base + i];
            int d = ei[E + base + i];
            val[i] = (unsigned)s | ((unsigned)(d & (CB - 1)) << 17);
            key[i] = (unsigned char)(d >> 10);
        }
    } else {
        const i32x2* ei2 = (const i32x2*)ei;
        for (int i = t; i < nE; i += 512) {
            int s = ei2[base + i][0];
            int d = ei2[E + base + i][0];
            val[i] = (unsigned)s | ((unsigned)(d & (CB - 1)) << 17);
            key[i] = (unsigned char)(d >> 10);
        }
    }
    __syncthreads();
    for (int i = t; i < nE; i += 512) atomicAdd(&cnt[key[i]], 1);
    __syncthreads();
    if (t < 256) pos[t] = cnt[t];
    __syncthreads();
    for (int d = 1; d < 256; d <<= 1) {
        int x = (t >= d && t < 256) ? pos[t - d] : 0;
        __syncthreads();
        if (t < 256) pos[t] += x;
        __syncthreads();
    }
    if (t < 256) cur[t] = pos[t] - cnt[t];          // exclusive offset
    if (t < NC) off_local[b * (NC + 1) + t] = pos[t] - cnt[t];
    if (t == 0) off_local[b * (NC + 1) + NC] = nE;
    __syncthreads();
    for (int i = t; i < nE; i += 512) {
        int k = key[i];
        int p = atomicAdd(&cur[k], 1);
        srt[p] = val[i];
    }
    __syncthreads();
    for (int i = t; i < nE; i += 512) sorted_all[base + i] = (int)srt[i];
}

// Per-coarse-bucket totals: column sums of the off-diff matrix.
__global__ __launch_bounds__(256) void k_colsum(const int* __restrict__ off_local,
                                                int* __restrict__ totals,
                                                int nchunk, int NC) {
    __shared__ int s[256];
    const int c = blockIdx.x;
    const int t = threadIdx.x;
    int sum = 0;
    for (int b = t; b < nchunk; b += 256) {
        int rb = b * (NC + 1);
        sum += off_local[rb + c + 1] - off_local[rb + c];
    }
    s[t] = sum;
    __syncthreads();
    for (int d = 128; d > 0; d >>= 1) {
        if (t < d) s[t] += s[t + d];
        __syncthreads();
    }
    if (t == 0) totals[c] = s[0];
}

// Exclusive scan of totals (NC <= 256) -> cbase; also rowp[n] = E.
__global__ __launch_bounds__(256) void k_cscan(const int* __restrict__ totals,
                                               int* __restrict__ cbase,
                                               int* __restrict__ rowp,
                                               int NC, int n) {
    __shared__ int s[256];
    const int t = threadIdx.x;
    int v = (t < NC) ? totals[t] : 0;
    s[t] = v;
    __syncthreads();
    for (int d = 1; d < 256; d <<= 1) {
        int x = (t >= d) ? s[t - d] : 0;
        __syncthreads();
        s[t] += x;
        __syncthreads();
    }
    if (t < NC) cbase[t] = s[t] - v;
    if (t == NC - 1) { cbase[NC] = s[t]; rowp[n] = s[t]; }
}

// ---------------------------------------------------------------------------
// Fine pass, 8 XCD-pinned sub-blocks per bucket.
// ---------------------------------------------------------------------------
__global__ __launch_bounds__(512) void k_fhist(const int* __restrict__ sorted_all,
                                               const int* __restrict__ off_local,
                                               int* __restrict__ gsub,
                                               int nchunk, int NC) {
    __shared__ int hist[CB];
    const int x = blockIdx.x & 7;
    const int s = (blockIdx.x >> 3) & 7;
    const int c = (blockIdx.x >> 6) * 8 + x;
    if (c >= NC) return;
    const int t = threadIdx.x;
    const int w = t >> 6, lane = t & 63;
    hist[t] = 0;
    hist[t + 512] = 0;
    __syncthreads();
    const int span = (nchunk + 7) / 8;
    const int b0 = s * span;
    const int b1 = min(nchunk, b0 + span);
    for (int b = b0 + w; b < b1; b += 8) {
        int rb = b * (NC + 1);
        int s0 = b * CHUNK + off_local[rb + c];
        int s1 = b * CHUNK + off_local[rb + c + 1];
        for (int i = s0 + lane; i < s1; i += 64)
            atomicAdd(&hist[((unsigned)sorted_all[i] >> 17) & (CB - 1)], 1);
    }
    __syncthreads();
    gsub[((size_t)c * 8 + s) * CB + t] = hist[t];
    gsub[((size_t)c * 8 + s) * CB + t + 512] = hist[t + 512];
}

// Per-bucket: total hist -> rowp/dinv; per-sub cursors scur (exact ranges).
__global__ __launch_bounds__(1024) void k_frowp(const int* __restrict__ gsub,
                                                const int* __restrict__ cbase,
                                                int* __restrict__ scur,
                                                int* __restrict__ rowp,
                                                float* __restrict__ dinv,
                                                int NC, int n) {
    __shared__ int ssum[CB];
    const int c = blockIdx.x;
    const int t = threadIdx.x;                 // = dloc
    int h[8];
    int tot = 0;
#pragma unroll
    for (int s = 0; s < 8; ++s) {
        h[s] = gsub[((size_t)c * 8 + s) * CB + t];
        tot += h[s];
    }
    ssum[t] = tot;
    __syncthreads();
    for (int d = 1; d < 1024; d <<= 1) {
        int x = (t >= d) ? ssum[t - d] : 0;
        __syncthreads();
        ssum[t] += x;
        __syncthreads();
    }
    int base = cbase[c] + ssum[t] - tot;       // exclusive within bucket
    const int node = c * CB + t;
    if (node < n) {
        rowp[node] = base;
        dinv[node] = rsqrtf((float)(tot + 1));  // +1 self loop
    }
    int run = base;
#pragma unroll
    for (int s = 0; s < 8; ++s) {
        scur[((size_t)c * 8 + s) * CB + t] = run;
        run += h[s];
    }
}

// Scatter: each sub-block writes its private, disjoint per-dloc ranges.
__global__ __launch_bounds__(512) void k_fscat(const int* __restrict__ sorted_all,
                                               const int* __restrict__ off_local,
                                               const int* __restrict__ scur,
                                               int* __restrict__ esrc,
                                               int nchunk, int NC) {
    __shared__ int cur[CB];
    const int x = blockIdx.x & 7;
    const int s = (blockIdx.x >> 3) & 7;
    const int c = (blockIdx.x >> 6) * 8 + x;
    if (c >= NC) return;
    const int t = threadIdx.x;
    const int w = t >> 6, lane = t & 63;
    cur[t] = scur[((size_t)c * 8 + s) * CB + t];
    cur[t + 512] = scur[((size_t)c * 8 + s) * CB + t + 512];
    __syncthreads();
    const int span = (nchunk + 7) / 8;
    const int b0 = s * span;
    const int b1 = min(nchunk, b0 + span);
    for (int b = b0 + w; b < b1; b += 8) {
        int rb = b * (NC + 1);
        int s0 = b * CHUNK + off_local[rb + c];
        int s1 = b * CHUNK + off_local[rb + c + 1];
        for (int i = s0 + lane; i < s1; i += 64) {
            unsigned v = (unsigned)sorted_all[i];
            int dl = (v >> 17) & (CB - 1);
            int p = atomicAdd(&cur[dl], 1);
            esrc[p] = (int)(v & 0x1FFFF);
        }
    }
}

// ---------------------------------------------------------------------------
// Register-tiled GEMM: G[n x 64](bf16) = (X[n x K_IN] * W) * dinv.
// ---------------------------------------------------------------------------
template <int K_IN, bool BF16IN>
__global__ __launch_bounds__(256) void k_gemm2(const void* __restrict__ Xv,
                                               const float* __restrict__ W,
                                               const float* __restrict__ dinv,
                                               unsigned short* __restrict__ G,
                                               int n) {
    __shared__ float Xs[64][33];
    __shared__ float Ws[32][64];
    const int t = threadIdx.x;
    const int tx = t & 15;
    const int ty = t >> 4;
    const int r0 = blockIdx.x * 64;

    float acc[4][4] = {};

    for (int kb = 0; kb < K_IN; kb += 32) {
        {
            const int kq = t & 7;
            const int rr = t >> 3;
#pragma unroll
            for (int it = 0; it < 2; ++it) {
                int r = r0 + rr + it * 32;
                int rc = r < n ? r : n - 1;
                float* xd = &Xs[rr + it * 32][kq * 4];
                if (BF16IN) {
                    const unsigned short* X = (const unsigned short*)Xv;
                    u16x4 xv = *(const u16x4*)(X + (size_t)rc * K_IN + kb + kq * 4);
                    xd[0] = bf2f(xv[0]); xd[1] = bf2f(xv[1]);
                    xd[2] = bf2f(xv[2]); xd[3] = bf2f(xv[3]);
                } else {
                    const float* X = (const float*)Xv;
                    float4 xv = *(const float4*)(X + (size_t)rc * K_IN + kb + kq * 4);
                    xd[0] = xv.x; xd[1] = xv.y; xd[2] = xv.z; xd[3] = xv.w;
                }
            }
        }
        {
            const int cq = t & 15;
            const int kr = t >> 4;
#pragma unroll
            for (int it = 0; it < 2; ++it) {
                float4 wv = *(const float4*)(W + (size_t)(kb + kr + it * 16) * 64 + cq * 4);
                *(float4*)&Ws[kr + it * 16][cq * 4] = wv;
            }
        }
        __syncthreads();
#pragma unroll 8
        for (int k = 0; k < 32; ++k) {
            float4 wv = *(const float4*)&Ws[k][tx * 4];
            float x0 = Xs[ty * 4 + 0][k];
            float x1 = Xs[ty * 4 + 1][k];
            float x2 = Xs[ty * 4 + 2][k];
            float x3 = Xs[ty * 4 + 3][k];
            acc[0][0] = fmaf(x0, wv.x, acc[0][0]);
            acc[0][1] = fmaf(x0, wv.y, acc[0][1]);
            acc[0][2] = fmaf(x0, wv.z, acc[0][2]);
            acc[0][3] = fmaf(x0, wv.w, acc[0][3]);
            acc[1][0] = fmaf(x1, wv.x, acc[1][0]);
            acc[1][1] = fmaf(x1, wv.y, acc[1][1]);
            acc[1][2] = fmaf(x1, wv.z, acc[1][2]);
            acc[1][3] = fmaf(x1, wv.w, acc[1][3]);
            acc[2][0] = fmaf(x2, wv.x, acc[2][0]);
            acc[2][1] = fmaf(x2, wv.y, acc[2][1]);
            acc[2][2] = fmaf(x2, wv.z, acc[2][2]);
            acc[2][3] = fmaf(x2, wv.w, acc[2][3]);
            acc[3][0] = fmaf(x3, wv.x, acc[3][0]);
            acc[3][1] = fmaf(x3, wv.y, acc[3][1]);
            acc[3][2] = fmaf(x3, wv.z, acc[3][2]);
            acc[3][3] = fmaf(x3, wv.w, acc[3][3]);
        }
        __syncthreads();
    }
#pragma unroll
    for (int j = 0; j < 4; ++j) {
        int r = r0 + ty * 4 + j;
        if (r < n) {
            float dv = dinv[r];
            union { unsigned short u[4]; uint2 v; } o;
            o.u[0] = f2bf(acc[j][0] * dv);
            o.u[1] = f2bf(acc[j][1] * dv);
            o.u[2] = f2bf(acc[j][2] * dv);
            o.u[3] = f2bf(acc[j][3] * dv);
            *(uint2*)(G + (size_t)r * 64 + tx * 4) = o.v;
        }
    }
}

// ---------------------------------------------------------------------------
// Aggregation (dual-row packed): wave = 2 edge streams x 32 feature-pair
// lanes; one instruction fetches 2 rows (2 x 128B lines). f32 accumulate,
// halves combined by shfl_xor(32). Self-loop on half 0 only.
// ---------------------------------------------------------------------------
template <bool RELU>
__global__ __launch_bounds__(256) void k_agg(const unsigned short* __restrict__ G,
                                             const int* __restrict__ rowp,
                                             const int* __restrict__ esrc,
                                             const float* __restrict__ dinv,
                                             const float* __restrict__ bias,
                                             void* __restrict__ OUTv, int n) {
    const int lane = threadIdx.x & 63;
    const int h = lane >> 5;                   // edge-stream half
    const int o = lane & 31;                   // feature pair index
    const int i = blockIdx.x * (blockDim.x >> 6) + (threadIdx.x >> 6);
    if (i >= n) return;
    const unsigned* __restrict__ Gu = (const unsigned*)G;   // row = 32 uints
    float a0 = 0.f, a1 = 0.f;
    if (h == 0) {
        unsigned sv = Gu[(size_t)i * 32 + o];              // self loop (once)
        a0 += bflo(sv); a1 += bfhi(sv);
    }
    int e = rowp[i] + h;
    const int e1 = rowp[i + 1];
    for (; e + 30 < e1; e += 32) {             // 16 rows per half per iter
        int s[16];
#pragma unroll
        for (int k = 0; k < 16; ++k) s[k] = esrc[e + 2 * k];
        unsigned v[16];
#pragma unroll
        for (int k = 0; k < 16; ++k) v[k] = Gu[(size_t)s[k] * 32 + o];
        float f0[8], f1[8];
#pragma unroll
        for (int k = 0; k < 8; ++k) {
            f0[k] = bflo(v[k]) + bflo(v[k + 8]);
            f1[k] = bfhi(v[k]) + bfhi(v[k + 8]);
        }
#pragma unroll
        for (int st = 4; st > 0; st >>= 1)
#pragma unroll
            for (int k = 0; k < st; ++k) { f0[k] += f0[k + st]; f1[k] += f1[k + st]; }
        a0 += f0[0]; a1 += f1[0];
    }
    for (; e + 6 < e1; e += 8) {               // 4 rows per half per iter
        int s[4];
#pragma unroll
        for (int k = 0; k < 4; ++k) s[k] = esrc[e + 2 * k];
#pragma unroll
        for (int k = 0; k < 4; ++k) {
            unsigned v = Gu[(size_t)s[k] * 32 + o];
            a0 += bflo(v); a1 += bfhi(v);
        }
    }
    for (; e < e1; e += 2) {
        unsigned v = Gu[(size_t)esrc[e] * 32 + o];
        a0 += bflo(v); a1 += bfhi(v);
    }
    a0 += __shfl_xor(a0, 32, 64);
    a1 += __shfl_xor(a1, 32, 64);
    if (h == 0) {
        float dv = dinv[i];
        float r0 = dv * a0 + bias[2 * o];
        float r1 = dv * a1 + bias[2 * o + 1];
        if (RELU) {
            r0 = fmaxf(r0, 0.f);
            r1 = fmaxf(r1, 0.f);
            unsigned pk = (unsigned)f2bf(r0) | ((unsigned)f2bf(r1) << 16);
            ((unsigned*)OUTv)[(size_t)i * 32 + o] = pk;
        } else {
            float2 r;
            r.x = r0; r.y = r1;
            *(float2*)((float*)OUTv + (size_t)i * 64 + 2 * o) = r;
        }
    }
}

extern "C" void kernel_launch(void* const* d_in, const int* in_sizes, int n_in,
                              void* d_out, int out_size, void* d_ws, size_t ws_size,
                              hipStream_t stream) {
    const float* x = (const float*)d_in[0];
    const int* ei = (const int*)d_in[1];
    const float* W1 = (const float*)d_in[2];
    const float* b1 = (const float*)d_in[3];
    const float* W2 = (const float*)d_in[4];
    const float* b2 = (const float*)d_in[5];
    float* out = (float*)d_out;

    const int N = in_sizes[0] / 128;          // requires N <= 131072 (17-bit src)
    const long long E = in_sizes[1] / 2;
    const int NCHUNK = (int)((E + CHUNK - 1) / CHUNK);
    const int NC = (N + CB - 1) / CB;                    // coarse buckets <= 128
    const int NBF = ((NC + 7) / 8) * 64;                 // fine-pass grid

    char* p = (char*)d_ws;
    size_t off = 0;
    auto take = [&](size_t bytes) -> void* {
        void* r = p + off;
        off += (bytes + 255) & ~(size_t)255;
        return r;
    };
    int* off_local = (int*)take((size_t)NCHUNK * (NC + 1) * 4);
    int* totals = (int*)take((size_t)NC * 4);
    int* cbase = (int*)take((size_t)(NC + 1) * 4);
    int* rowp = (int*)take((size_t)(N + 1) * 4);
    float* dinv = (float*)take((size_t)N * 4);
    int* sorted_all = (int*)take((size_t)NCHUNK * CHUNK * 4);
    int* esrc = (int*)take((size_t)E * 4);
    int* gsub = (int*)take((size_t)NC * 8 * CB * 4);
    int* scur = (int*)take((size_t)NC * 8 * CB * 4);
    unsigned short* gbuf1 = (unsigned short*)take((size_t)N * 64 * 2);
    unsigned short* gbuf2 = (unsigned short*)take((size_t)N * 64 * 2);
    unsigned short* hbuf = (unsigned short*)take((size_t)N * 64 * 2);
    (void)ws_size; (void)n_in; (void)out_size;

    k_localsort<<<NCHUNK, 512, 0, stream>>>(ei, sorted_all, off_local, E, NC);
    k_colsum<<<NC, 256, 0, stream>>>(off_local, totals, NCHUNK, NC);
    k_cscan<<<1, 256, 0, stream>>>(totals, cbase, rowp, NC, N);
    k_fhist<<<NBF, 512, 0, stream>>>(sorted_all, off_local, gsub, NCHUNK, NC);
    k_frowp<<<NC, 1024, 0, stream>>>(gsub, cbase, scur, rowp, dinv, NC, N);
    k_fscat<<<NBF, 512, 0, stream>>>(sorted_all, off_local, scur, esrc, NCHUNK, NC);

    k_gemm2<128, false><<<(N + 63) / 64, 256, 0, stream>>>(x, W1, dinv, gbuf1, N);
    k_agg<true><<<(N + 3) / 4, 256, 0, stream>>>(gbuf1, rowp, esrc, dinv, b1, hbuf, N);
    k_gemm2<64, true><<<(N + 63) / 64, 256, 0, stream>>>(hbuf, W2, dinv, gbuf2, N);
    k_agg<false><<<(N + 3) / 4, 256, 0, stream>>>(gbuf2, rowp, esrc, dinv, b2, out, N);
}